// Round 3
// baseline (1118.436 us; speedup 1.0000x reference)
//
#include <hip/hip_runtime.h>
#include <math.h>

#define BATCH 4
#define CH    48
#define QKVC  144
#define HID   192
#define HEADS 8
#define IMG   256
#define HWSZ  65536

typedef unsigned short bf16u;

__device__ __forceinline__ float bf2f(bf16u u) { return __uint_as_float(((unsigned)u) << 16); }
__device__ __forceinline__ bf16u f2bf(float f) {
    unsigned u = __float_as_uint(f);
    unsigned r = u + 0x7fffu + ((u >> 16) & 1u);
    return (bf16u)(r >> 16);
}

// ---------------------------------------------------------------------------
// K0: transpose w_f2 (48x192) -> w2t (192x48)
// ---------------------------------------------------------------------------
__global__ __launch_bounds__(256) void k0_w2t(const float* __restrict__ w2, float* __restrict__ w2t)
{
    const int e = blockIdx.x * 256 + threadIdx.x;
    if (e < CH * HID) {
        const int o = e / HID, gc = e - o * HID;
        w2t[gc * CH + o] = w2[e];
    }
}

// ---------------------------------------------------------------------------
// K1: per-pixel LayerNorm over C=48 + 1x1 conv -> 144 qkv channels (bf16 out)
// ---------------------------------------------------------------------------
__global__ __launch_bounds__(256) void k1_ln_qkv(
    const float* __restrict__ x, const float* __restrict__ ln_g, const float* __restrict__ ln_b,
    const float* __restrict__ wq, const float* __restrict__ bq,
    bf16u* __restrict__ qkv)
{
    const int tid = threadIdx.x;
    const int b = blockIdx.x >> 8;
    const int p = ((blockIdx.x & 255) << 8) | tid;
    const float* xb = x + ((size_t)b * CH << 16) + p;
    float y[CH];
    float mu = 0.f;
#pragma unroll
    for (int c = 0; c < CH; ++c) { y[c] = xb[(size_t)c << 16]; mu += y[c]; }
    mu *= (1.0f / CH);
    float var = 0.f;
#pragma unroll
    for (int c = 0; c < CH; ++c) { float d = y[c] - mu; var += d * d; }
    const float rs = rsqrtf(var * (1.0f / CH) + 1e-5f);
#pragma unroll
    for (int c = 0; c < CH; ++c) y[c] = (y[c] - mu) * rs * ln_g[c] + ln_b[c];

    bf16u* qb = qkv + ((size_t)b * QKVC << 16) + p;
    for (int o = 0; o < QKVC; ++o) {
        float acc = bq[o];
#pragma unroll
        for (int c = 0; c < CH; ++c) acc += wq[o * CH + c] * y[c];
        qb[(size_t)o << 16] = f2bf(acc);
    }
}

// raw 9-tap loader (bf16 plane, zero 'SAME' padding); py wave-uniform
__device__ __forceinline__ void ldtaps(const bf16u* __restrict__ base, int py, int px, bf16u t[9])
{
    const int idx = (py << 8) + px;
#pragma unroll
    for (int dy = -1; dy <= 1; ++dy) {
        const bool okY = (unsigned)(py + dy) < 256u;
#pragma unroll
        for (int dx = -1; dx <= 1; ++dx) {
            bf16u v = 0;
            if (okY && (unsigned)(px + dx) < 256u) v = base[idx + (dy << 8) + dx];
            t[(dy + 1) * 3 + dx + 1] = v;
        }
    }
}

// ---------------------------------------------------------------------------
// K2: depthwise 3x3 for one head's 18 channels (6q,6k,6v) from bf16 qkv.
// 512 threads = 64x8 tile. Writes dw'd v (bf16); block-reduces Gram+norms.
// ---------------------------------------------------------------------------
__global__ __launch_bounds__(512, 4) void k2_dw_gram(
    const bf16u* __restrict__ qkv, const float* __restrict__ wdw, const float* __restrict__ bdw,
    bf16u* __restrict__ vout, float* __restrict__ stats)
{
    __shared__ float red[8][48];
    const int tid = threadIdx.x;
    int blk = blockIdx.x;
    const int tx = blk & 3;        blk >>= 2;
    const int ty = blk & 31;       blk >>= 5;
    const int h  = blk & 7;        blk >>= 3;
    const int b  = blk;
    const int px = (tx << 6) | (tid & 63);
    const int py = (ty << 3) | (tid >> 6);     // wave-uniform
    const int idx = (py << 8) + px;

    float q[6], k[6];
#pragma unroll
    for (int s = 0; s < 3; ++s) {
        bf16u t[6][9];
#pragma unroll
        for (int j = 0; j < 6; ++j) {
            const int cg = s * 48 + h * 6 + j;
            ldtaps(qkv + ((size_t)(b * QKVC + cg) << 16), py, px, t[j]);
        }
#pragma unroll
        for (int j = 0; j < 6; ++j) {
            const int cg = s * 48 + h * 6 + j;
            const float* w9 = wdw + cg * 9;
            float a = bdw[cg];
#pragma unroll
            for (int i = 0; i < 9; ++i) a += bf2f(t[j][i]) * w9[i];
            if (s == 0) q[j] = a;
            else if (s == 1) k[j] = a;
            else vout[((size_t)(b * CH + h * 6 + j) << 16) + idx] = f2bf(a);
        }
    }

    float S[48];
#pragma unroll
    for (int c = 0; c < 6; ++c)
#pragma unroll
        for (int d = 0; d < 6; ++d) S[c * 6 + d] = q[c] * k[d];
#pragma unroll
    for (int c = 0; c < 6; ++c) { S[36 + c] = q[c] * q[c]; S[42 + c] = k[c] * k[c]; }

    const int lane = tid & 63, wv = tid >> 6;
#pragma unroll
    for (int i = 0; i < 48; ++i) {
        float r = S[i];
        for (int o = 32; o; o >>= 1) r += __shfl_down(r, o);
        if (lane == 0) red[wv][i] = r;
    }
    __syncthreads();
    if (tid < 48) {
        float s = 0.f;
#pragma unroll
        for (int w = 0; w < 8; ++w) s += red[w][tid];
        atomicAdd(&stats[((size_t)b * HEADS + h) * 48 + tid], s);
    }
}

// ---------------------------------------------------------------------------
// K3: cosine-sim logits -> softmax -> attn; fold with W_proj into M[b] (48x48)
// ---------------------------------------------------------------------------
__global__ __launch_bounds__(256) void k3_attn(
    const float* __restrict__ stats, const float* __restrict__ scale,
    const float* __restrict__ wproj, float* __restrict__ M)
{
    const int b = blockIdx.x;
    __shared__ float attn[HEADS][6][6];
    const int tid = threadIdx.x;
    if (tid < 48) {
        const int h = tid / 6, c = tid - h * 6;
        const float* st = stats + ((size_t)b * HEADS + h) * 48;
        const float qn = fmaxf(sqrtf(st[36 + c]), 1e-12f);
        const float sc = scale[h];
        float s[6]; float mx = -1e30f;
#pragma unroll
        for (int d = 0; d < 6; ++d) {
            const float kn = fmaxf(sqrtf(st[42 + d]), 1e-12f);
            s[d] = st[c * 6 + d] / (qn * kn) * sc;
            mx = fmaxf(mx, s[d]);
        }
        float sum = 0.f;
#pragma unroll
        for (int d = 0; d < 6; ++d) { s[d] = expf(s[d] - mx); sum += s[d]; }
        const float inv = 1.f / sum;
#pragma unroll
        for (int d = 0; d < 6; ++d) attn[h][c][d] = s[d] * inv;
    }
    __syncthreads();
    for (int e = tid; e < 48 * 48; e += 256) {
        const int o = e / 48; const int i = e - o * 48;
        const int h = i / 6,  d = i - h * 6;
        float acc = 0.f;
#pragma unroll
        for (int c = 0; c < 6; ++c) acc += wproj[o * 48 + h * 6 + c] * attn[h][c][d];
        M[(size_t)b * 2304 + e] = acc;
    }
}

// ---------------------------------------------------------------------------
// K45: x1 = x + M_b@v + b_proj (fp32 -> d_out), then LN + 1x1 -> h1 (bf16)
// ---------------------------------------------------------------------------
__global__ __launch_bounds__(256) void k45_pvproj_ln_f1(
    const float* __restrict__ x, const bf16u* __restrict__ vbuf,
    const float* __restrict__ M, const float* __restrict__ bproj,
    const float* __restrict__ ln_g, const float* __restrict__ ln_b,
    const float* __restrict__ w1, const float* __restrict__ b1,
    float* __restrict__ x1, bf16u* __restrict__ h1)
{
    const int tid = threadIdx.x;
    const int b = blockIdx.x >> 8;
    const int p = ((blockIdx.x & 255) << 8) | tid;
    const float* Mb = M + (size_t)b * 2304;
    float v[CH];
    const bf16u* vb = vbuf + ((size_t)b * CH << 16) + p;
#pragma unroll
    for (int c = 0; c < CH; ++c) v[c] = bf2f(vb[(size_t)c << 16]);
    const float* xb = x + ((size_t)b * CH << 16) + p;
    float* ob = x1 + ((size_t)b * CH << 16) + p;

    float y[CH];
    float mu = 0.f;
    for (int o = 0; o < CH; ++o) {
        float acc = bproj[o];
#pragma unroll
        for (int c = 0; c < CH; ++c) acc += Mb[o * CH + c] * v[c];
        acc += xb[(size_t)o << 16];
        ob[(size_t)o << 16] = acc;
        y[o] = acc; mu += acc;
    }
    mu *= (1.0f / CH);
    float var = 0.f;
#pragma unroll
    for (int c = 0; c < CH; ++c) { float d = y[c] - mu; var += d * d; }
    const float rs = rsqrtf(var * (1.0f / CH) + 1e-5f);
#pragma unroll
    for (int c = 0; c < CH; ++c) y[c] = (y[c] - mu) * rs * ln_g[c] + ln_b[c];

    bf16u* hb = h1 + ((size_t)b * HID << 16) + p;
    for (int o = 0; o < HID; ++o) {
        float acc = b1[o];
#pragma unroll
        for (int c = 0; c < CH; ++c) acc += w1[o * CH + c] * y[c];
        hb[(size_t)o << 16] = f2bf(acc);
    }
}

// ---------------------------------------------------------------------------
// K6: dw3x3 + exact GELU + 1x1 conv partial over 96 channels, 2-way channel
// split across blocks, software-pipelined taps; atomicAdd into d_out.
// ---------------------------------------------------------------------------
__global__ __launch_bounds__(512, 4) void k6_ffn2(
    const bf16u* __restrict__ h1, const float* __restrict__ wfdw, const float* __restrict__ bfdw,
    const float* __restrict__ w2t, const float* __restrict__ b2,
    float* __restrict__ xio)
{
    const int tid = threadIdx.x;
    int blk = blockIdx.x;
    const int tx = blk & 3;        blk >>= 2;
    const int ty = blk & 31;       blk >>= 5;
    const int sp = blk & 1;        blk >>= 1;
    const int b  = blk;
    const int px = (tx << 6) | (tid & 63);
    const int py = (ty << 3) | (tid >> 6);     // wave-uniform
    const int idx = (py << 8) + px;
    const int gc0 = sp * 96;

    float acc[CH];
#pragma unroll
    for (int o = 0; o < CH; ++o) acc[o] = sp ? 0.f : b2[o];

    bf16u us[9];
    ldtaps(h1 + ((size_t)(b * HID + gc0) << 16), py, px, us);

    for (int c = 0; c < 96; ++c) {
        const int gc = gc0 + c;
        // issue next channel's taps before consuming current (1-deep pipeline)
        bf16u un[9];
        const int gn = gc + (c < 95 ? 1 : 0);
        ldtaps(h1 + ((size_t)(b * HID + gn) << 16), py, px, un);

        const float* w9 = wfdw + gc * 9;
        float d = bfdw[gc];
#pragma unroll
        for (int i = 0; i < 9; ++i) d += bf2f(us[i]) * w9[i];
        const float g = 0.5f * d * (1.f + erff(d * 0.70710678118654752f));
        const float* wrow = w2t + gc * CH;
#pragma unroll
        for (int o = 0; o < CH; ++o) acc[o] += wrow[o] * g;
#pragma unroll
        for (int i = 0; i < 9; ++i) us[i] = un[i];
    }

    float* ob = xio + ((size_t)b * CH << 16) + idx;
#pragma unroll
    for (int o = 0; o < CH; ++o) atomicAdd(&ob[(size_t)o << 16], acc[o]);
}

// ---------------------------------------------------------------------------
extern "C" void kernel_launch(void* const* d_in, const int* in_sizes, int n_in,
                              void* d_out, int out_size, void* d_ws, size_t ws_size,
                              hipStream_t stream)
{
    const float* x      = (const float*)d_in[0];
    const float* ln1_g  = (const float*)d_in[1];
    const float* ln1_b  = (const float*)d_in[2];
    const float* w_qkv  = (const float*)d_in[3];
    const float* b_qkv  = (const float*)d_in[4];
    const float* w_dw   = (const float*)d_in[5];
    const float* b_dw   = (const float*)d_in[6];
    const float* scale  = (const float*)d_in[7];
    const float* w_proj = (const float*)d_in[8];
    const float* b_proj = (const float*)d_in[9];
    const float* ln2_g  = (const float*)d_in[10];
    const float* ln2_b  = (const float*)d_in[11];
    const float* w_f1   = (const float*)d_in[12];
    const float* b_f1   = (const float*)d_in[13];
    const float* w_fdw  = (const float*)d_in[14];
    const float* b_fdw  = (const float*)d_in[15];
    const float* w_f2   = (const float*)d_in[16];
    const float* b_f2   = (const float*)d_in[17];
    float* out = (float*)d_out;

    // Workspace (bytes):
    //   [0)            qkv bf16 (B*144*HW*2 = 75.5MB), reused as h1 bf16 (B*192*HW*2 = 100.7MB)
    //   [100663296)    vbuf bf16 (B*48*HW*2 = 25.2MB)
    //   [125829120)    stats f32 (1536, pad 8192B)
    //   [125837312)    M f32 (B*2304)
    //   [125874176)    w2t f32 (192*48)
    char* wsb = (char*)d_ws;
    bf16u* qkv   = (bf16u*)(wsb);                    // also h1
    bf16u* vbuf  = (bf16u*)(wsb + 100663296);
    float* stats = (float*)(wsb + 125829120);
    float* M     = (float*)(wsb + 125837312);
    float* w2t   = (float*)(wsb + 125874176);

    hipMemsetAsync(stats, 0, 1536 * sizeof(float), stream);

    k0_w2t          <<<dim3(36),                  dim3(256), 0, stream>>>(w_f2, w2t);
    k1_ln_qkv       <<<dim3(BATCH * 256),         dim3(256), 0, stream>>>(x, ln1_g, ln1_b, w_qkv, b_qkv, qkv);
    k2_dw_gram      <<<dim3(BATCH * HEADS * 128), dim3(512), 0, stream>>>(qkv, w_dw, b_dw, vbuf, stats);
    k3_attn         <<<dim3(BATCH),               dim3(256), 0, stream>>>(stats, scale, w_proj, M);
    k45_pvproj_ln_f1<<<dim3(BATCH * 256),         dim3(256), 0, stream>>>(x, vbuf, M, b_proj,
                                                                          ln2_g, ln2_b, w_f1, b_f1, out, qkv);
    k6_ffn2         <<<dim3(BATCH * 256),         dim3(512), 0, stream>>>(qkv, w_fdw, b_fdw, w2t, b_f2, out);
}